// Round 3
// baseline (1373.176 us; speedup 1.0000x reference)
//
#include <hip/hip_runtime.h>
#include <stdint.h>

// GlobalEmdModel: mlp1(128->256->512->512) -> segmax -> segbias trick ->
// mlp2(X@W4a + sb[seg] -> 512 -> segmax) ; bf16 MFMA GEMMs, fp32 epilogues.
// R3: 256x256 tile, 8 waves, BK=32, 4-deep LDS ring, counted vmcnt(8),
//     st_16x32 LDS swizzle (both-sides), setprio around MFMA clusters.

typedef __bf16 bf16;
typedef __bf16 bf16x4 __attribute__((ext_vector_type(4)));
typedef __bf16 bf16x8 __attribute__((ext_vector_type(8)));
typedef float f32x4 __attribute__((ext_vector_type(4)));

#define N_PTS 400000
#define ORD_NEG_INF 0x007FFFFFu  // f2ord(-inf)

__device__ __forceinline__ unsigned f2ord(float f) {
  unsigned u = __float_as_uint(f);
  return (u & 0x80000000u) ? ~u : (u | 0x80000000u);
}
__device__ __forceinline__ float ord2f(unsigned o) {
  unsigned u = (o & 0x80000000u) ? (o ^ 0x80000000u) : ~o;
  return __uint_as_float(u);
}

__device__ __forceinline__ void gld16(const bf16* g, bf16* l) {
  __builtin_amdgcn_global_load_lds((const __attribute__((address_space(1))) void*)g,
                                   (__attribute__((address_space(3))) void*)l, 16, 0, 0);
}

__global__ void k_init(unsigned* g_ord, unsigned* out_u) {
  int i = blockIdx.x * 256 + threadIdx.x;
  if (i < 64 * 512) { g_ord[i] = ORD_NEG_INF; out_u[i] = ORD_NEG_INF; }
}

__global__ void k_convX(const float* __restrict__ x, bf16* __restrict__ y, long n4) {
  long i = (long)blockIdx.x * 256 + threadIdx.x;
  long stride = (long)gridDim.x * 256;
  for (; i < n4; i += stride) {
    float4 v = ((const float4*)x)[i];
    bf16x4 o = {(bf16)v.x, (bf16)v.y, (bf16)v.z, (bf16)v.w};
    ((bf16x4*)y)[i] = o;
  }
}

// W [K][Nout] fp32 -> Wt [Nout][K] bf16
__global__ void k_convWt(const float* __restrict__ W, bf16* __restrict__ Wt, int K, int Nout) {
  int idx = blockIdx.x * 256 + threadIdx.x;
  if (idx < K * Nout) {
    int k = idx / Nout, c = idx - k * Nout;
    Wt[(size_t)c * K + k] = (bf16)W[idx];
  }
}

// sb[s][c] = b4[c] + sum_j g[s][j] * W4[128+j][c]
__global__ void k_segbias(const unsigned* __restrict__ g_ord, const float* __restrict__ W4,
                          const float* __restrict__ b4, float* __restrict__ sb) {
  const int s = blockIdx.x, c = threadIdx.x;
  __shared__ float gs[512];
  gs[c] = ord2f(g_ord[s * 512 + c]);
  __syncthreads();
  float acc = b4[c];
  for (int j = 0; j < 512; ++j) acc = fmaf(gs[j], W4[(size_t)(128 + j) * 512 + c], acc);
  sb[s * 512 + c] = acc;
}

__global__ void k_decode(unsigned* p, int n) {
  int i = blockIdx.x * 256 + threadIdx.x;
  if (i < n) { float f = ord2f(p[i]); ((float*)p)[i] = f; }
}

// 256x256 tile, 8 waves (wr 0..1 x wc 0..3), per-wave 128x64 output.
// LDS: 4-K-tile ring, each K-tile {A:16KB, B:16KB} as 16 subtiles of 16rows x 32cols,
// st_16x32 swizzle: stored 16-col block = logical block ^ (subtile_row>>3).
// BIASMODE: 0 = per-col bias[], 1 = per-(seg,col) sb[] (NOUT 512)
// EPI: 0 = store bf16 to out, 1 = segmax atomicMax(ordered-uint) into outAtomic
template <int BIASMODE, bool RELU, int EPI, int K, int NOUT>
__launch_bounds__(512, 2)
__global__ void k_gemm(const bf16* __restrict__ A, const bf16* __restrict__ Bt,
                       const float* __restrict__ bias, const int* __restrict__ ids,
                       long row_off, bf16* __restrict__ out,
                       unsigned* __restrict__ outAtomic) {
  constexpr int KT = K / 32;
  constexpr int NBX = NOUT / 256;
  __shared__ __align__(16) bf16 sAll[4][2][8192];  // [ring][A/B][16KB]
  __shared__ int sIds[256];
  const int tid = threadIdx.x;
  const int wid = tid >> 6, lane = tid & 63;
  const int wr = wid >> 2, wc = wid & 3;
  const int lr = lane & 15, lk = lane >> 4;

  // linear id (N fastest) -> bijective XCD swizzle (m204)
  const int nwg = NBX * (int)gridDim.y;
  const int orig = (int)blockIdx.y * NBX + (int)blockIdx.x;
  const int q = nwg >> 3, r = nwg & 7;
  const int xcd = orig & 7, lid = orig >> 3;
  const int wg = (xcd < r ? xcd * (q + 1) : r * (q + 1) + (xcd - r) * q) + lid;
  const int n0 = (wg % NBX) * 256;
  const int m0 = (wg / NBX) * 256;

  if constexpr (BIASMODE == 1 || EPI == 1) {
    if (tid < 256) {
      long gi = row_off + m0 + tid;
      if (gi > (long)N_PTS - 1) gi = (long)N_PTS - 1;
      sIds[tid] = ids[gi];
    }
  }

  // ---- staging geometry: wave wid stages subtiles {2wid, 2wid+1} of A and B.
  // Within a subtile, lane l writes bytes [16l,16l+16): row sr=l>>2, stored 8-col
  // chunk l&3. Pre-swizzle the SOURCE column so reads can swizzle identically:
  // logical 16-col block = stored block ((l&3)>>1) ^ (sr>>3), sr>>3 = (l>>5)&1.
  const int rg0 = wid * 2;
  const int ssr = lane >> 2;
  const int scb = ((lane & 3) >> 1) ^ ((lane >> 5) & 1);
  const int csrc = scb * 16 + (lane & 1) * 8;
  const bf16* gA = A + (size_t)(m0 + rg0 * 16 + ssr) * K + csrc;
  const bf16* gB = Bt + (size_t)(n0 + rg0 * 16 + ssr) * K + csrc;

  auto STAGE = [&](int kt) {
    const int b = kt & 3;
    const int ko = kt * 32;
    bf16* la = &sAll[b][0][rg0 * 512];
    bf16* lb = &sAll[b][1][rg0 * 512];
    gld16(gA + ko, la);
    gld16(gA + (size_t)16 * K + ko, la + 512);
    gld16(gB + ko, lb);
    gld16(gB + (size_t)16 * K + ko, lb + 512);
  };

  // ---- fragment read offsets (elements), swizzled 16-col block on read
  const int cread = (lk * 8) ^ ((lr & 8) ? 16 : 0);
  const int foA = (wr * 8) * 512 + lr * 32 + cread;  // + i*512
  const int foB = (wc * 4) * 512 + lr * 32 + cread;  // + j*512

  f32x4 acc[8][4];
#pragma unroll
  for (int i = 0; i < 8; ++i)
#pragma unroll
    for (int j = 0; j < 4; ++j) acc[i][j] = {0.f, 0.f, 0.f, 0.f};

  STAGE(0); STAGE(1); STAGE(2);  // 12 vmem ops in flight

#pragma unroll 1
  for (int kt = 0; kt < KT; ++kt) {
    const int b = kt & 3;
    if (kt <= KT - 3) asm volatile("s_waitcnt vmcnt(8)" ::: "memory");
    else if (kt == KT - 2) asm volatile("s_waitcnt vmcnt(4)" ::: "memory");
    else asm volatile("s_waitcnt vmcnt(0)" ::: "memory");
    __syncthreads();
    if (kt <= KT - 4) STAGE(kt + 3);  // targets buf (kt+3)&3 == (kt-1)&3: free since barrier
    const bf16* Ab = &sAll[b][0][0];
    const bf16* Bb = &sAll[b][1][0];
    bf16x8 bfr[4], af[4];
#pragma unroll
    for (int j = 0; j < 4; ++j) bfr[j] = *(const bf16x8*)(Bb + foB + j * 512);
#pragma unroll
    for (int i = 0; i < 4; ++i) af[i] = *(const bf16x8*)(Ab + foA + i * 512);
    __builtin_amdgcn_s_setprio(1);
#pragma unroll
    for (int i = 0; i < 4; ++i)
#pragma unroll
      for (int j = 0; j < 4; ++j)
        acc[i][j] = __builtin_amdgcn_mfma_f32_16x16x32_bf16(af[i], bfr[j], acc[i][j], 0, 0, 0);
    __builtin_amdgcn_s_setprio(0);
    __syncthreads();
#pragma unroll
    for (int i = 0; i < 4; ++i) af[i] = *(const bf16x8*)(Ab + foA + (4 + i) * 512);
    __builtin_amdgcn_s_setprio(1);
#pragma unroll
    for (int i = 0; i < 4; ++i)
#pragma unroll
      for (int j = 0; j < 4; ++j)
        acc[4 + i][j] = __builtin_amdgcn_mfma_f32_16x16x32_bf16(af[i], bfr[j], acc[4 + i][j], 0, 0, 0);
    __builtin_amdgcn_s_setprio(0);
  }

  if constexpr (EPI == 0) {
#pragma unroll
    for (int j = 0; j < 4; ++j) {
      const int col = n0 + wc * 64 + j * 16 + lr;
      float bcol = (BIASMODE == 0) ? bias[col] : 0.f;
#pragma unroll
      for (int i = 0; i < 8; ++i) {
#pragma unroll
        for (int q2 = 0; q2 < 4; ++q2) {
          const int rl = wr * 128 + i * 16 + lk * 4 + q2;
          float v = acc[i][j][q2];
          if constexpr (BIASMODE == 0) v += bcol;
          else v += bias[(size_t)sIds[rl] * 512 + col];
          if constexpr (RELU) v = fmaxf(v, 0.f);
          out[(size_t)(m0 + rl) * NOUT + col] = (bf16)v;
        }
      }
    }
  } else {
    const int sLo = sIds[wr * 128], sHi = sIds[wr * 128 + 127];
#pragma unroll
    for (int j = 0; j < 4; ++j) {
      const int col = n0 + wc * 64 + j * 16 + lr;
      const float bcol = bias[col];
      for (int s = sLo; s <= sHi; ++s) {
        float m = -__builtin_inff();
#pragma unroll
        for (int i = 0; i < 8; ++i)
#pragma unroll
          for (int q2 = 0; q2 < 4; ++q2) {
            const int rl = wr * 128 + i * 16 + lk * 4 + q2;
            const bool rv = (row_off + m0 + rl) < (long)N_PTS;  // pad rows share clamped id
            float v = acc[i][j][q2] + bcol;
            m = (sIds[rl] == s && rv) ? fmaxf(m, v) : m;
          }
        m = fmaxf(m, __shfl_xor(m, 16));
        m = fmaxf(m, __shfl_xor(m, 32));
        if (lane < 16) atomicMax(&outAtomic[(size_t)s * 512 + col], f2ord(m));
      }
    }
  }
}

static inline long lmin(long a, long b) { return a < b ? a : b; }

extern "C" void kernel_launch(void* const* d_in, const int* in_sizes, int n_in,
                              void* d_out, int out_size, void* d_ws, size_t ws_size,
                              hipStream_t stream) {
  const float* pos = (const float*)d_in[0];
  const int* ids = (const int*)d_in[1];
  const float* W1 = (const float*)d_in[2]; const float* b1 = (const float*)d_in[3];
  const float* W2 = (const float*)d_in[4]; const float* b2 = (const float*)d_in[5];
  const float* W3 = (const float*)d_in[6]; const float* b3 = (const float*)d_in[7];
  const float* W4 = (const float*)d_in[8]; const float* b4 = (const float*)d_in[9];
  const float* W5 = (const float*)d_in[10]; const float* b5 = (const float*)d_in[11];

  char* ws = (char*)d_ws;
  size_t off = 0;
  auto alloc = [&](size_t bytes) -> char* {
    off = (off + 255) & ~(size_t)255;
    char* p = ws + off; off += bytes; return p;
  };
  bf16* Wt1  = (bf16*)alloc(128 * 256 * 2);
  bf16* Wt2  = (bf16*)alloc(256 * 512 * 2);
  bf16* Wt3  = (bf16*)alloc(512 * 512 * 2);
  bf16* Wt4a = (bf16*)alloc(128 * 512 * 2);
  bf16* Wt5  = (bf16*)alloc(512 * 512 * 2);
  unsigned* g_ord = (unsigned*)alloc(64 * 512 * 4);
  float* sb = (float*)alloc(64 * 512 * 4);

  const size_t per_row = (128 + 256 + 512) * 2;
  size_t fixed_end = (off + 255) & ~(size_t)255;
  long avail = (long)ws_size - (long)fixed_end - 8192;
  long maxrows = avail / (long)per_row;
  long chunk = (maxrows - 256) & ~255L;  // chunk itself multiple of 256; +256 pad rows
  if (chunk > N_PTS) chunk = N_PTS;
  if (chunk < 256) chunk = 256;
  long rows_alloc = chunk + 256;

  bf16* Xbf = (bf16*)alloc((size_t)rows_alloc * 128 * 2);
  bf16* h1  = (bf16*)alloc((size_t)rows_alloc * 256 * 2);
  bf16* h2  = (bf16*)alloc((size_t)rows_alloc * 512 * 2);  // also z1 in phase 2

  const int nChunks = (int)((N_PTS + chunk - 1) / chunk);

  k_init<<<dim3(128), dim3(256), 0, stream>>>(g_ord, (unsigned*)d_out);
  k_convWt<<<dim3((128 * 256 + 255) / 256), dim3(256), 0, stream>>>(W1, Wt1, 128, 256);
  k_convWt<<<dim3((256 * 512 + 255) / 256), dim3(256), 0, stream>>>(W2, Wt2, 256, 512);
  k_convWt<<<dim3((512 * 512 + 255) / 256), dim3(256), 0, stream>>>(W3, Wt3, 512, 512);
  k_convWt<<<dim3((128 * 512 + 255) / 256), dim3(256), 0, stream>>>(W4, Wt4a, 128, 512);
  k_convWt<<<dim3((512 * 512 + 255) / 256), dim3(256), 0, stream>>>(W5, Wt5, 512, 512);

  // phase 1: mlp1 + fused segmax -> g_ord
  for (long o = 0; o < N_PTS; o += chunk) {
    long rows = lmin(chunk, N_PTS - o);
    long n4 = rows * 32;
    long cb = lmin(2048, (n4 + 255) / 256);
    k_convX<<<dim3((unsigned)cb), dim3(256), 0, stream>>>(pos + o * 128, Xbf, n4);
    unsigned mb = (unsigned)((rows + 255) / 256);
    k_gemm<0, true, 0, 128, 256><<<dim3(1, mb), dim3(512), 0, stream>>>(Xbf, Wt1, b1, ids, o, h1, nullptr);
    k_gemm<0, true, 0, 256, 512><<<dim3(2, mb), dim3(512), 0, stream>>>(h1, Wt2, b2, ids, o, h2, nullptr);
    k_gemm<0, false, 1, 512, 512><<<dim3(2, mb), dim3(512), 0, stream>>>(h2, Wt3, b3, ids, o, nullptr, g_ord);
  }
  k_segbias<<<dim3(64), dim3(512), 0, stream>>>(g_ord, W4, b4, sb);
  // phase 2: z1 = relu(X@W4a + sb[seg]); out = segmax(z1@W5 + b5)
  for (long o = 0; o < N_PTS; o += chunk) {
    long rows = lmin(chunk, N_PTS - o);
    if (nChunks > 1) {
      long n4 = rows * 32;
      long cb = lmin(2048, (n4 + 255) / 256);
      k_convX<<<dim3((unsigned)cb), dim3(256), 0, stream>>>(pos + o * 128, Xbf, n4);
    }
    unsigned mb = (unsigned)((rows + 255) / 256);
    k_gemm<1, true, 0, 128, 512><<<dim3(2, mb), dim3(512), 0, stream>>>(Xbf, Wt4a, sb, ids, o, h2, nullptr);
    k_gemm<0, false, 1, 512, 512><<<dim3(2, mb), dim3(512), 0, stream>>>(h2, Wt5, b5, ids, o, nullptr, (unsigned*)d_out);
  }
  k_decode<<<dim3(128), dim3(256), 0, stream>>>((unsigned*)d_out, 64 * 512);
}

// Round 4
// 1342.105 us; speedup vs baseline: 1.0232x; 1.0232x over previous
//
#include <hip/hip_runtime.h>
#include <stdint.h>

// GlobalEmdModel: mlp1(128->256->512->512) -> segmax -> segbias trick ->
// mlp2(X@W4a + sb[seg] -> 512 -> segmax) ; bf16 MFMA GEMMs, fp32 epilogues.
// R4: 256x256 tile, 8 waves, BK=32, 4-deep LDS ring, counted vmcnt,
//     cross-tile fragment pipelining: MFMA starts at barrier on regs read
//     last iteration; af2 reads hide under cluster-1 MFMA; 1 barrier/K-tile.

typedef __bf16 bf16;
typedef __bf16 bf16x4 __attribute__((ext_vector_type(4)));
typedef __bf16 bf16x8 __attribute__((ext_vector_type(8)));
typedef float f32x4 __attribute__((ext_vector_type(4)));

#define N_PTS 400000
#define ORD_NEG_INF 0x007FFFFFu  // f2ord(-inf)

__device__ __forceinline__ unsigned f2ord(float f) {
  unsigned u = __float_as_uint(f);
  return (u & 0x80000000u) ? ~u : (u | 0x80000000u);
}
__device__ __forceinline__ float ord2f(unsigned o) {
  unsigned u = (o & 0x80000000u) ? (o ^ 0x80000000u) : ~o;
  return __uint_as_float(u);
}

__device__ __forceinline__ void gld16(const bf16* g, bf16* l) {
  __builtin_amdgcn_global_load_lds((const __attribute__((address_space(1))) void*)g,
                                   (__attribute__((address_space(3))) void*)l, 16, 0, 0);
}

__global__ void k_init(unsigned* g_ord, unsigned* out_u) {
  int i = blockIdx.x * 256 + threadIdx.x;
  if (i < 64 * 512) { g_ord[i] = ORD_NEG_INF; out_u[i] = ORD_NEG_INF; }
}

__global__ void k_convX(const float* __restrict__ x, bf16* __restrict__ y, long n4) {
  long i = (long)blockIdx.x * 256 + threadIdx.x;
  long stride = (long)gridDim.x * 256;
  for (; i < n4; i += stride) {
    float4 v = ((const float4*)x)[i];
    bf16x4 o = {(bf16)v.x, (bf16)v.y, (bf16)v.z, (bf16)v.w};
    ((bf16x4*)y)[i] = o;
  }
}

// W [K][Nout] fp32 -> Wt [Nout][K] bf16
__global__ void k_convWt(const float* __restrict__ W, bf16* __restrict__ Wt, int K, int Nout) {
  int idx = blockIdx.x * 256 + threadIdx.x;
  if (idx < K * Nout) {
    int k = idx / Nout, c = idx - k * Nout;
    Wt[(size_t)c * K + k] = (bf16)W[idx];
  }
}

// sb[s][c] = b4[c] + sum_j g[s][j] * W4[128+j][c]
__global__ void k_segbias(const unsigned* __restrict__ g_ord, const float* __restrict__ W4,
                          const float* __restrict__ b4, float* __restrict__ sb) {
  const int s = blockIdx.x, c = threadIdx.x;
  __shared__ float gs[512];
  gs[c] = ord2f(g_ord[s * 512 + c]);
  __syncthreads();
  float acc = b4[c];
  for (int j = 0; j < 512; ++j) acc = fmaf(gs[j], W4[(size_t)(128 + j) * 512 + c], acc);
  sb[s * 512 + c] = acc;
}

__global__ void k_decode(unsigned* p, int n) {
  int i = blockIdx.x * 256 + threadIdx.x;
  if (i < n) { float f = ord2f(p[i]); ((float*)p)[i] = f; }
}

// 256x256 tile, 8 waves (wr 0..1 x wc 0..3), per-wave 128x64 output.
// LDS: 4-K-tile ring, each K-tile {A:16KB, B:16KB} as 16 subtiles of 16rows x 32cols,
// swizzle: stored 16-col block = logical block ^ bit (both-sides, verified R3).
// BIASMODE: 0 = per-col bias[], 1 = per-(seg,col) sb[] (NOUT 512)
// EPI: 0 = store bf16 to out, 1 = segmax atomicMax(ordered-uint) into outAtomic
template <int BIASMODE, bool RELU, int EPI, int K, int NOUT>
__launch_bounds__(512, 2)
__global__ void k_gemm(const bf16* __restrict__ A, const bf16* __restrict__ Bt,
                       const float* __restrict__ bias, const int* __restrict__ ids,
                       long row_off, bf16* __restrict__ out,
                       unsigned* __restrict__ outAtomic) {
  constexpr int KT = K / 32;
  constexpr int NBX = NOUT / 256;
  __shared__ __align__(16) bf16 sAll[4][2][8192];  // [ring][A/B][16KB]
  __shared__ int sIds[256];
  const int tid = threadIdx.x;
  const int wid = tid >> 6, lane = tid & 63;
  const int wr = wid >> 2, wc = wid & 3;
  const int lr = lane & 15, lk = lane >> 4;

  // linear id (N fastest) -> bijective XCD swizzle (m204)
  const int nwg = NBX * (int)gridDim.y;
  const int orig = (int)blockIdx.y * NBX + (int)blockIdx.x;
  const int q = nwg >> 3, r = nwg & 7;
  const int xcd = orig & 7, lid = orig >> 3;
  const int wg = (xcd < r ? xcd * (q + 1) : r * (q + 1) + (xcd - r) * q) + lid;
  const int n0 = (wg % NBX) * 256;
  const int m0 = (wg / NBX) * 256;

  if constexpr (BIASMODE == 1 || EPI == 1) {
    if (tid < 256) {
      long gi = row_off + m0 + tid;
      if (gi > (long)N_PTS - 1) gi = (long)N_PTS - 1;
      sIds[tid] = ids[gi];
    }
  }

  // ---- staging geometry (verified R3): wave wid stages subtiles {2wid, 2wid+1}.
  const int rg0 = wid * 2;
  const int ssr = lane >> 2;
  const int scb = ((lane & 3) >> 1) ^ ((lane >> 5) & 1);
  const int csrc = scb * 16 + (lane & 1) * 8;
  const bf16* gA = A + (size_t)(m0 + rg0 * 16 + ssr) * K + csrc;
  const bf16* gB = Bt + (size_t)(n0 + rg0 * 16 + ssr) * K + csrc;

  auto STAGE = [&](int kt) {
    const int b = kt & 3;
    const int ko = kt * 32;
    bf16* la = &sAll[b][0][rg0 * 512];
    bf16* lb = &sAll[b][1][rg0 * 512];
    gld16(gA + ko, la);
    gld16(gA + (size_t)16 * K + ko, la + 512);
    gld16(gB + ko, lb);
    gld16(gB + (size_t)16 * K + ko, lb + 512);
  };

  // ---- fragment read offsets (elements), swizzled 16-col block on read
  const int cread = (lk * 8) ^ ((lr & 8) ? 16 : 0);
  const int foA = (wr * 8) * 512 + lr * 32 + cread;  // + i*512
  const int foB = (wc * 4) * 512 + lr * 32 + cread;  // + j*512

  f32x4 acc[8][4];
#pragma unroll
  for (int i = 0; i < 8; ++i)
#pragma unroll
    for (int j = 0; j < 4; ++j) acc[i][j] = {0.f, 0.f, 0.f, 0.f};

  STAGE(0); STAGE(1); STAGE(2);  // 12 vmem ops in flight
  asm volatile("s_waitcnt vmcnt(8)" ::: "memory");  // stage(0) landed (mine)
  __syncthreads();                                   // everyone's stage(0) landed

  // fragments for tile 0 (persist across iterations; always compile-time indexed)
  bf16x8 af[4], bfr[4];
  {
    const bf16* Ab = &sAll[0][0][0];
    const bf16* Bb = &sAll[0][1][0];
#pragma unroll
    for (int j = 0; j < 4; ++j) bfr[j] = *(const bf16x8*)(Bb + foB + j * 512);
#pragma unroll
    for (int i = 0; i < 4; ++i) af[i] = *(const bf16x8*)(Ab + foA + i * 512);
  }

#pragma unroll 1
  for (int kt = 0; kt < KT; ++kt) {
    // steady: all stages <= kt+1 landed (last outstanding is stage(kt+2));
    // tail: drain. Needed for the end-of-iter reads of buf kt+1.
    if (kt < KT - 2) asm volatile("s_waitcnt vmcnt(4)" ::: "memory");
    else asm volatile("s_waitcnt vmcnt(0)" ::: "memory");
    __syncthreads();
    if (kt + 3 < KT) STAGE(kt + 3);  // writes buf (kt-1)&3: reads done pre-barrier

    const bf16* Ab = &sAll[kt & 3][0][0];
    bf16x8 af2[4];
#pragma unroll
    for (int i = 0; i < 4; ++i) af2[i] = *(const bf16x8*)(Ab + foA + (4 + i) * 512);

    __builtin_amdgcn_s_setprio(1);
#pragma unroll
    for (int i = 0; i < 4; ++i)
#pragma unroll
      for (int j = 0; j < 4; ++j)
        acc[i][j] = __builtin_amdgcn_mfma_f32_16x16x32_bf16(af[i], bfr[j], acc[i][j], 0, 0, 0);
    __builtin_amdgcn_s_setprio(0);

    __builtin_amdgcn_s_setprio(1);
#pragma unroll
    for (int i = 0; i < 4; ++i)
#pragma unroll
      for (int j = 0; j < 4; ++j)
        acc[4 + i][j] = __builtin_amdgcn_mfma_f32_16x16x32_bf16(af2[i], bfr[j], acc[4 + i][j], 0, 0, 0);
    __builtin_amdgcn_s_setprio(0);

    if (kt + 1 < KT) {  // prefetch next tile's fragments (buf landed via top vmcnt)
      const bf16* An = &sAll[(kt + 1) & 3][0][0];
      const bf16* Bn = &sAll[(kt + 1) & 3][1][0];
#pragma unroll
      for (int j = 0; j < 4; ++j) bfr[j] = *(const bf16x8*)(Bn + foB + j * 512);
#pragma unroll
      for (int i = 0; i < 4; ++i) af[i] = *(const bf16x8*)(An + foA + i * 512);
    }
  }

  if constexpr (EPI == 0) {
#pragma unroll
    for (int j = 0; j < 4; ++j) {
      const int col = n0 + wc * 64 + j * 16 + lr;
      float bcol = (BIASMODE == 0) ? bias[col] : 0.f;
#pragma unroll
      for (int i = 0; i < 8; ++i) {
#pragma unroll
        for (int q2 = 0; q2 < 4; ++q2) {
          const int rl = wr * 128 + i * 16 + lk * 4 + q2;
          float v = acc[i][j][q2];
          if constexpr (BIASMODE == 0) v += bcol;
          else v += bias[(size_t)sIds[rl] * 512 + col];
          if constexpr (RELU) v = fmaxf(v, 0.f);
          out[(size_t)(m0 + rl) * NOUT + col] = (bf16)v;
        }
      }
    }
  } else {
    const int sLo = sIds[wr * 128], sHi = sIds[wr * 128 + 127];
#pragma unroll
    for (int j = 0; j < 4; ++j) {
      const int col = n0 + wc * 64 + j * 16 + lr;
      const float bcol = bias[col];
      for (int s = sLo; s <= sHi; ++s) {
        float m = -__builtin_inff();
#pragma unroll
        for (int i = 0; i < 8; ++i)
#pragma unroll
          for (int q2 = 0; q2 < 4; ++q2) {
            const int rl = wr * 128 + i * 16 + lk * 4 + q2;
            const bool rv = (row_off + m0 + rl) < (long)N_PTS;  // pad rows share clamped id
            float v = acc[i][j][q2] + bcol;
            m = (sIds[rl] == s && rv) ? fmaxf(m, v) : m;
          }
        m = fmaxf(m, __shfl_xor(m, 16));
        m = fmaxf(m, __shfl_xor(m, 32));
        if (lane < 16) atomicMax(&outAtomic[(size_t)s * 512 + col], f2ord(m));
      }
    }
  }
}

static inline long lmin(long a, long b) { return a < b ? a : b; }

extern "C" void kernel_launch(void* const* d_in, const int* in_sizes, int n_in,
                              void* d_out, int out_size, void* d_ws, size_t ws_size,
                              hipStream_t stream) {
  const float* pos = (const float*)d_in[0];
  const int* ids = (const int*)d_in[1];
  const float* W1 = (const float*)d_in[2]; const float* b1 = (const float*)d_in[3];
  const float* W2 = (const float*)d_in[4]; const float* b2 = (const float*)d_in[5];
  const float* W3 = (const float*)d_in[6]; const float* b3 = (const float*)d_in[7];
  const float* W4 = (const float*)d_in[8]; const float* b4 = (const float*)d_in[9];
  const float* W5 = (const float*)d_in[10]; const float* b5 = (const float*)d_in[11];

  char* ws = (char*)d_ws;
  size_t off = 0;
  auto alloc = [&](size_t bytes) -> char* {
    off = (off + 255) & ~(size_t)255;
    char* p = ws + off; off += bytes; return p;
  };
  bf16* Wt1  = (bf16*)alloc(128 * 256 * 2);
  bf16* Wt2  = (bf16*)alloc(256 * 512 * 2);
  bf16* Wt3  = (bf16*)alloc(512 * 512 * 2);
  bf16* Wt4a = (bf16*)alloc(128 * 512 * 2);
  bf16* Wt5  = (bf16*)alloc(512 * 512 * 2);
  unsigned* g_ord = (unsigned*)alloc(64 * 512 * 4);
  float* sb = (float*)alloc(64 * 512 * 4);

  const size_t per_row = (128 + 256 + 512) * 2;
  size_t fixed_end = (off + 255) & ~(size_t)255;
  long avail = (long)ws_size - (long)fixed_end - 8192;
  long maxrows = avail / (long)per_row;
  long chunk = (maxrows - 256) & ~255L;  // chunk multiple of 256; +256 pad rows
  if (chunk > N_PTS) chunk = N_PTS;
  if (chunk < 256) chunk = 256;
  long rows_alloc = chunk + 256;

  bf16* Xbf = (bf16*)alloc((size_t)rows_alloc * 128 * 2);
  bf16* h1  = (bf16*)alloc((size_t)rows_alloc * 256 * 2);
  bf16* h2  = (bf16*)alloc((size_t)rows_alloc * 512 * 2);  // also z1 in phase 2

  const int nChunks = (int)((N_PTS + chunk - 1) / chunk);

  k_init<<<dim3(128), dim3(256), 0, stream>>>(g_ord, (unsigned*)d_out);
  k_convWt<<<dim3((128 * 256 + 255) / 256), dim3(256), 0, stream>>>(W1, Wt1, 128, 256);
  k_convWt<<<dim3((256 * 512 + 255) / 256), dim3(256), 0, stream>>>(W2, Wt2, 256, 512);
  k_convWt<<<dim3((512 * 512 + 255) / 256), dim3(256), 0, stream>>>(W3, Wt3, 512, 512);
  k_convWt<<<dim3((128 * 512 + 255) / 256), dim3(256), 0, stream>>>(W4, Wt4a, 128, 512);
  k_convWt<<<dim3((512 * 512 + 255) / 256), dim3(256), 0, stream>>>(W5, Wt5, 512, 512);

  // phase 1: mlp1 + fused segmax -> g_ord
  for (long o = 0; o < N_PTS; o += chunk) {
    long rows = lmin(chunk, N_PTS - o);
    long n4 = rows * 32;
    long cb = lmin(2048, (n4 + 255) / 256);
    k_convX<<<dim3((unsigned)cb), dim3(256), 0, stream>>>(pos + o * 128, Xbf, n4);
    unsigned mb = (unsigned)((rows + 255) / 256);
    k_gemm<0, true, 0, 128, 256><<<dim3(1, mb), dim3(512), 0, stream>>>(Xbf, Wt1, b1, ids, o, h1, nullptr);
    k_gemm<0, true, 0, 256, 512><<<dim3(2, mb), dim3(512), 0, stream>>>(h1, Wt2, b2, ids, o, h2, nullptr);
    k_gemm<0, false, 1, 512, 512><<<dim3(2, mb), dim3(512), 0, stream>>>(h2, Wt3, b3, ids, o, nullptr, g_ord);
  }
  k_segbias<<<dim3(64), dim3(512), 0, stream>>>(g_ord, W4, b4, sb);
  // phase 2: z1 = relu(X@W4a + sb[seg]); out = segmax(z1@W5 + b5)
  for (long o = 0; o < N_PTS; o += chunk) {
    long rows = lmin(chunk, N_PTS - o);
    if (nChunks > 1) {
      long n4 = rows * 32;
      long cb = lmin(2048, (n4 + 255) / 256);
      k_convX<<<dim3((unsigned)cb), dim3(256), 0, stream>>>(pos + o * 128, Xbf, n4);
    }
    unsigned mb = (unsigned)((rows + 255) / 256);
    k_gemm<1, true, 0, 128, 512><<<dim3(2, mb), dim3(512), 0, stream>>>(Xbf, Wt4a, sb, ids, o, h2, nullptr);
    k_gemm<0, false, 1, 512, 512><<<dim3(2, mb), dim3(512), 0, stream>>>(h2, Wt5, b5, ids, o, nullptr, (unsigned*)d_out);
  }
  k_decode<<<dim3(128), dim3(256), 0, stream>>>((unsigned*)d_out, 64 * 512);
}